// Round 4
// baseline (4795.158 us; speedup 1.0000x reference)
//
#include <hip/hip_runtime.h>

#define H 51
#define TIN 512
#define TTOT 544      // TIN + future(32)
#define BTILE 8

__device__ __forceinline__ float fast_rcp(float x) { return __builtin_amdgcn_rcpf(x); }
__device__ __forceinline__ float sigf(float x)  { return fast_rcp(1.0f + __expf(-x)); }
__device__ __forceinline__ float tanhf_(float x){ return 1.0f - 2.0f * fast_rcp(1.0f + __expf(2.0f * x)); }

// R4 design: 1024 thr/block (16 waves = 4 waves/EU -> allocator is FORCED to
// <=128 VGPRs, which is the budget it insisted on in R2/R3). Per-thread state
// halved so 128 suffices: weights 84 floats (4g x 7k x 3m, k = q+8j, q in
// [0,8)), acc 16 (4g x 4b). Biases/W_ih1 live in LDS, not regs.
//   lane bits: [0:2]=q (k-phase), [3]=bh (batch half), [4:5]+wave = u (0..63)
//   After 3-stage shfl_xor reduce-scatter, lane owns gate-pair gp=q&1 of
//   (u, my_b); partner-lane exchange computes c on both lanes consistently.
__global__ __launch_bounds__(1024)
void lstm_seq(
    const float* __restrict__ input,   // [2048][512]
    const float* __restrict__ W_ih1,   // [204]
    const float* __restrict__ W_hh1,   // [204][51]
    const float* __restrict__ b_ih1,   // [204]
    const float* __restrict__ b_hh1,   // [204]
    const float* __restrict__ W_ih2,   // [204][51]
    const float* __restrict__ W_hh2,   // [204][51]
    const float* __restrict__ b_ih2,   // [204]
    const float* __restrict__ b_hh2,   // [204]
    const float* __restrict__ W_lin,   // [51]
    const float* __restrict__ b_lin,   // [1]
    float* __restrict__ out)           // [2048][544]
{
    __shared__ __align__(16) float sH1[2][64][8];   // [buf][k/unit][b]
    __shared__ __align__(16) float sH2[2][64][8];
    __shared__ __align__(16) float sB1[64][4];      // b_ih1+b_hh1, [u][gate]
    __shared__ __align__(16) float sWX[64][4];      // W_ih1, [u][gate]
    __shared__ __align__(16) float sB2[64][4];      // b_ih2+b_hh2
    __shared__ float sWlin[64];
    __shared__ float sXfb[8];

    const int tid  = threadIdx.x;
    const int lane = tid & 63;
    const int wv   = tid >> 6;                 // 0..15
    const int u    = wv * 4 + (lane >> 4);     // 0..63
    const int q    = lane & 7;                 // k-phase
    const int bh   = (lane >> 3) & 1;          // batch half
    const int gp   = q & 1;                    // owned gate-pair after butterfly
    const int my_b = bh * 4 + ((q & 2) ? 2 : 0) + ((q & 4) ? 1 : 0);
    const int b0   = blockIdx.x * BTILE;
    const int ur   = (u < H) ? u : (H - 1);    // clamp pad units (finite garbage)

    // ---- persistent register weights: k = q + 8*j, j in [0,7) ----
    float w1[4][7], w2a[4][7], w2b[4][7];      // 84 floats
    #pragma unroll
    for (int g = 0; g < 4; ++g) {
        const int r = g * H + ur;
        #pragma unroll
        for (int j = 0; j < 7; ++j) {
            const int k = q + 8 * j;
            const bool ok = (k < H);           // zero pad col: kills garbage h[k>=51]
            w1 [g][j] = ok ? W_hh1[r * H + k] : 0.0f;
            w2a[g][j] = ok ? W_ih2[r * H + k] : 0.0f;
            w2b[g][j] = ok ? W_hh2[r * H + k] : 0.0f;
        }
    }
    const float blin = b_lin[0];

    if (tid < 256) {
        const int uu = tid >> 2, g = tid & 3;
        const int r = g * H + ((uu < H) ? uu : (H - 1));
        sB1[uu][g] = b_ih1[r] + b_hh1[r];
        sWX[uu][g] = W_ih1[r];
        sB2[uu][g] = b_ih2[r] + b_hh2[r];
    }
    if (tid < 64) sWlin[tid] = (tid < H) ? W_lin[tid] : 0.0f;
    {
        float* p1 = &sH1[0][0][0];
        float* p2 = &sH2[0][0][0];
        for (int i = tid; i < 2 * 64 * 8; i += 1024) { p1[i] = 0.0f; p2[i] = 0.0f; }
    }

    const float* xptr = input + (size_t)(b0 + my_b) * TIN;
    const int loff = q * 8 + bh * 4;           // lane offset into sH row space
    float c1 = 0.0f, c2 = 0.0f;
    __syncthreads();

    for (int t = 0; t < TTOT; ++t) {
        const int cur = t & 1, nxt = cur ^ 1;

        float x = (t < TIN) ? xptr[t] : sXfb[my_b];

        float a[4][4];                          // [gate][b-in-half]
        float z0, z1;

        // ================= layer 1: W_hh1 @ h1 =================
        #pragma unroll
        for (int g = 0; g < 4; ++g)
            #pragma unroll
            for (int i = 0; i < 4; ++i) a[g][i] = 0.0f;
        {
            const float* h1c = &sH1[cur][0][0] + loff;
            #pragma unroll
            for (int j = 0; j < 7; ++j) {
                float4 h4 = *(const float4*)(h1c + 64 * j);
                #pragma unroll
                for (int g = 0; g < 4; ++g) {
                    a[g][0] += w1[g][j] * h4.x;
                    a[g][1] += w1[g][j] * h4.y;
                    a[g][2] += w1[g][j] * h4.z;
                    a[g][3] += w1[g][j] * h4.w;
                }
            }
        }
        // 3-stage reduce-scatter over q: gates -> b-pair -> b
        {
            float k2[2][4];
            #pragma unroll
            for (int g2 = 0; g2 < 2; ++g2)
                #pragma unroll
                for (int i = 0; i < 4; ++i) {
                    float lo = a[g2][i], hi = a[g2 + 2][i];
                    float got = __shfl_xor(gp ? lo : hi, 1);
                    k2[g2][i] = (gp ? hi : lo) + got;
                }
            float k3[2][2];
            #pragma unroll
            for (int g2 = 0; g2 < 2; ++g2)
                #pragma unroll
                for (int i = 0; i < 2; ++i) {
                    float lo = k2[g2][i], hi = k2[g2][i + 2];
                    float got = __shfl_xor((q & 2) ? lo : hi, 2);
                    k3[g2][i] = ((q & 2) ? hi : lo) + got;
                }
            #pragma unroll
            for (int g2 = 0; g2 < 2; ++g2) {
                float lo = k3[g2][0], hi = k3[g2][1];
                float got = __shfl_xor((q & 4) ? lo : hi, 4);
                float z = ((q & 4) ? hi : lo) + got;
                if (g2 == 0) z0 = z; else z1 = z;
            }
        }
        // finalize L1: gp0 lane: z0->i, z1->f ; gp1 lane: z0->g, z1->o
        {
            float2 bi = *(const float2*)&sB1[u][2 * gp];
            float2 wx = *(const float2*)&sWX[u][2 * gp];
            z0 += bi.x + wx.x * x;
            z1 += bi.y + wx.y * x;
            float E = __expf(gp ? 2.0f * z0 : -z0);
            float R = fast_rcp(1.0f + E);
            float v0 = gp ? (1.0f - 2.0f * R) : R;   // gp0: sig(z0)=I, gp1: tanh(z0)=G
            float v1 = sigf(z1);                      // gp0: F, gp1: O
            float e0 = __shfl_xor(v0, 1);             // gp0 gets G, gp1 gets I
            float e1 = __shfl_xor(v1, 1);             // gp0 gets O, gp1 gets F
            float I = gp ? e0 : v0;
            float F = gp ? e1 : v1;
            float G = gp ? v0 : e0;
            float O = gp ? v1 : e1;
            c1 = F * c1 + I * G;                      // identical on both gp lanes
            if (!gp) sH1[nxt][u][my_b] = O * tanhf_(c1);
        }
        __syncthreads();

        // ============ layer 2: W_ih2 @ h1_new + W_hh2 @ h2 ============
        #pragma unroll
        for (int g = 0; g < 4; ++g)
            #pragma unroll
            for (int i = 0; i < 4; ++i) a[g][i] = 0.0f;
        {
            const float* han = &sH1[nxt][0][0] + loff;
            const float* hbc = &sH2[cur][0][0] + loff;
            #pragma unroll
            for (int j = 0; j < 7; ++j) {
                float4 ha = *(const float4*)(han + 64 * j);
                float4 hb = *(const float4*)(hbc + 64 * j);
                #pragma unroll
                for (int g = 0; g < 4; ++g) {
                    a[g][0] += w2a[g][j] * ha.x + w2b[g][j] * hb.x;
                    a[g][1] += w2a[g][j] * ha.y + w2b[g][j] * hb.y;
                    a[g][2] += w2a[g][j] * ha.z + w2b[g][j] * hb.z;
                    a[g][3] += w2a[g][j] * ha.w + w2b[g][j] * hb.w;
                }
            }
        }
        {
            float k2[2][4];
            #pragma unroll
            for (int g2 = 0; g2 < 2; ++g2)
                #pragma unroll
                for (int i = 0; i < 4; ++i) {
                    float lo = a[g2][i], hi = a[g2 + 2][i];
                    float got = __shfl_xor(gp ? lo : hi, 1);
                    k2[g2][i] = (gp ? hi : lo) + got;
                }
            float k3[2][2];
            #pragma unroll
            for (int g2 = 0; g2 < 2; ++g2)
                #pragma unroll
                for (int i = 0; i < 2; ++i) {
                    float lo = k2[g2][i], hi = k2[g2][i + 2];
                    float got = __shfl_xor((q & 2) ? lo : hi, 2);
                    k3[g2][i] = ((q & 2) ? hi : lo) + got;
                }
            #pragma unroll
            for (int g2 = 0; g2 < 2; ++g2) {
                float lo = k3[g2][0], hi = k3[g2][1];
                float got = __shfl_xor((q & 4) ? lo : hi, 4);
                float z = ((q & 4) ? hi : lo) + got;
                if (g2 == 0) z0 = z; else z1 = z;
            }
        }
        {
            float2 bi = *(const float2*)&sB2[u][2 * gp];
            z0 += bi.x;
            z1 += bi.y;
            float E = __expf(gp ? 2.0f * z0 : -z0);
            float R = fast_rcp(1.0f + E);
            float v0 = gp ? (1.0f - 2.0f * R) : R;
            float v1 = sigf(z1);
            float e0 = __shfl_xor(v0, 1);
            float e1 = __shfl_xor(v1, 1);
            float I = gp ? e0 : v0;
            float F = gp ? e1 : v1;
            float G = gp ? v0 : e0;
            float O = gp ? v1 : e1;
            c2 = F * c2 + I * G;
            if (!gp) sH2[nxt][u][my_b] = O * tanhf_(c2);
        }
        __syncthreads();

        // ---- output head: out = W_lin @ h2_new + b_lin (wave 0) ----
        if (tid < 64) {
            const int b = tid >> 3, kc = tid & 7;
            float p = 0.0f;
            #pragma unroll
            for (int jj = 0; jj < 8; ++jj) {
                const int k = kc + 8 * jj;                 // rows >= 51: sWlin = 0
                p += sWlin[k] * sH2[nxt][k][b];
            }
            p += __shfl_xor(p, 1);
            p += __shfl_xor(p, 2);
            p += __shfl_xor(p, 4);
            if (kc == 0) {
                float val = p + blin;
                out[(size_t)(b0 + b) * TTOT + t] = val;
                sXfb[b] = val;
            }
        }
        // sXfb only consumed at t+1 >= TIN; buffer rotation is safe without
        // this barrier otherwise (see R3 analysis).
        if (t >= TIN - 1) __syncthreads();
    }
}

extern "C" void kernel_launch(void* const* d_in, const int* in_sizes, int n_in,
                              void* d_out, int out_size, void* d_ws, size_t ws_size,
                              hipStream_t stream) {
    const float* input = (const float*)d_in[0];
    const float* W_ih1 = (const float*)d_in[1];
    const float* W_hh1 = (const float*)d_in[2];
    const float* b_ih1 = (const float*)d_in[3];
    const float* b_hh1 = (const float*)d_in[4];
    const float* W_ih2 = (const float*)d_in[5];
    const float* W_hh2 = (const float*)d_in[6];
    const float* b_ih2 = (const float*)d_in[7];
    const float* b_hh2 = (const float*)d_in[8];
    const float* W_lin = (const float*)d_in[9];
    const float* b_lin = (const float*)d_in[10];
    // d_in[11] = future (=32), compiled in.
    float* out = (float*)d_out;

    lstm_seq<<<dim3(256), dim3(1024), 0, stream>>>(input, W_ih1, W_hh1, b_ih1, b_hh1,
                                                   W_ih2, W_hh2, b_ih2, b_hh2,
                                                   W_lin, b_lin, out);
}

// Round 5
// 4745.647 us; speedup vs baseline: 1.0104x; 1.0104x over previous
//
#include <hip/hip_runtime.h>

#define H 51
#define TIN 512
#define TTOT 544      // TIN + future(32)
#define BTILE 8

__device__ __forceinline__ float fast_rcp(float x) { return __builtin_amdgcn_rcpf(x); }
__device__ __forceinline__ float sigf(float x)  { return fast_rcp(1.0f + __expf(-x)); }
__device__ __forceinline__ float tanhf_(float x){ return 1.0f - 2.0f * fast_rcp(1.0f + __expf(2.0f * x)); }

// R5 = R4 + amdgpu_waves_per_eu(4,4).
// Allocator heuristic (observed R2/R4): it targets 2 workgroups/CU. With
// 1024-thr blocks that meant 64 VGPRs -> scratch spill (R4: FETCH 4.25 GB).
// Pinning waves/EU to exactly 4 (= ONE 16-wave block/CU) grants the 128-VGPR
// budget this kernel was designed for: 84 weight floats + 16 acc + temps ~ 120.
//   lane bits: [0:2]=q (k-phase, k=q+8j), [3]=bh (batch half), [4:5]+wave = u
//   3-stage shfl_xor reduce-scatter -> lane owns gate-pair gp=q&1 of (u,my_b);
//   partner exchange computes c identically on both gp lanes.
__global__ __launch_bounds__(1024)
__attribute__((amdgpu_waves_per_eu(4, 4)))
void lstm_seq(
    const float* __restrict__ input,   // [2048][512]
    const float* __restrict__ W_ih1,   // [204]
    const float* __restrict__ W_hh1,   // [204][51]
    const float* __restrict__ b_ih1,   // [204]
    const float* __restrict__ b_hh1,   // [204]
    const float* __restrict__ W_ih2,   // [204][51]
    const float* __restrict__ W_hh2,   // [204][51]
    const float* __restrict__ b_ih2,   // [204]
    const float* __restrict__ b_hh2,   // [204]
    const float* __restrict__ W_lin,   // [51]
    const float* __restrict__ b_lin,   // [1]
    float* __restrict__ out)           // [2048][544]
{
    __shared__ __align__(16) float sH1[2][64][8];   // [buf][k/unit][b]
    __shared__ __align__(16) float sH2[2][64][8];
    __shared__ __align__(16) float sB1[64][4];      // b_ih1+b_hh1, [u][gate]
    __shared__ __align__(16) float sWX[64][4];      // W_ih1, [u][gate]
    __shared__ __align__(16) float sB2[64][4];      // b_ih2+b_hh2
    __shared__ float sWlin[64];
    __shared__ float sXfb[8];

    const int tid  = threadIdx.x;
    const int lane = tid & 63;
    const int wv   = tid >> 6;                 // 0..15
    const int u    = wv * 4 + (lane >> 4);     // 0..63
    const int q    = lane & 7;                 // k-phase
    const int bh   = (lane >> 3) & 1;          // batch half
    const int gp   = q & 1;                    // owned gate-pair after butterfly
    const int my_b = bh * 4 + ((q & 2) ? 2 : 0) + ((q & 4) ? 1 : 0);
    const int b0   = blockIdx.x * BTILE;
    const int ur   = (u < H) ? u : (H - 1);    // clamp pad units (finite garbage)

    // ---- persistent register weights: k = q + 8*j, j in [0,7) ----
    float w1[4][7], w2a[4][7], w2b[4][7];      // 84 floats
    #pragma unroll
    for (int g = 0; g < 4; ++g) {
        const int r = g * H + ur;
        #pragma unroll
        for (int j = 0; j < 7; ++j) {
            const int k = q + 8 * j;
            const bool ok = (k < H);           // zero pad col: kills garbage h[k>=51]
            w1 [g][j] = ok ? W_hh1[r * H + k] : 0.0f;
            w2a[g][j] = ok ? W_ih2[r * H + k] : 0.0f;
            w2b[g][j] = ok ? W_hh2[r * H + k] : 0.0f;
        }
    }
    const float blin = b_lin[0];

    if (tid < 256) {
        const int uu = tid >> 2, g = tid & 3;
        const int r = g * H + ((uu < H) ? uu : (H - 1));
        sB1[uu][g] = b_ih1[r] + b_hh1[r];
        sWX[uu][g] = W_ih1[r];
        sB2[uu][g] = b_ih2[r] + b_hh2[r];
    }
    if (tid < 64) sWlin[tid] = (tid < H) ? W_lin[tid] : 0.0f;
    {
        float* p1 = &sH1[0][0][0];
        float* p2 = &sH2[0][0][0];
        for (int i = tid; i < 2 * 64 * 8; i += 1024) { p1[i] = 0.0f; p2[i] = 0.0f; }
    }

    const float* xptr = input + (size_t)(b0 + my_b) * TIN;
    const int loff = q * 8 + bh * 4;           // lane offset into sH row space
    float c1 = 0.0f, c2 = 0.0f;
    __syncthreads();

    for (int t = 0; t < TTOT; ++t) {
        const int cur = t & 1, nxt = cur ^ 1;

        float x = (t < TIN) ? xptr[t] : sXfb[my_b];

        float a[4][4];                          // [gate][b-in-half]
        float z0, z1;

        // ================= layer 1: W_hh1 @ h1 =================
        #pragma unroll
        for (int g = 0; g < 4; ++g)
            #pragma unroll
            for (int i = 0; i < 4; ++i) a[g][i] = 0.0f;
        {
            const float* h1c = &sH1[cur][0][0] + loff;
            #pragma unroll
            for (int j = 0; j < 7; ++j) {
                float4 h4 = *(const float4*)(h1c + 64 * j);
                #pragma unroll
                for (int g = 0; g < 4; ++g) {
                    a[g][0] += w1[g][j] * h4.x;
                    a[g][1] += w1[g][j] * h4.y;
                    a[g][2] += w1[g][j] * h4.z;
                    a[g][3] += w1[g][j] * h4.w;
                }
            }
        }
        // 3-stage reduce-scatter over q: gates -> b-pair -> b
        {
            float k2[2][4];
            #pragma unroll
            for (int g2 = 0; g2 < 2; ++g2)
                #pragma unroll
                for (int i = 0; i < 4; ++i) {
                    float lo = a[g2][i], hi = a[g2 + 2][i];
                    float got = __shfl_xor(gp ? lo : hi, 1);
                    k2[g2][i] = (gp ? hi : lo) + got;
                }
            float k3[2][2];
            #pragma unroll
            for (int g2 = 0; g2 < 2; ++g2)
                #pragma unroll
                for (int i = 0; i < 2; ++i) {
                    float lo = k2[g2][i], hi = k2[g2][i + 2];
                    float got = __shfl_xor((q & 2) ? lo : hi, 2);
                    k3[g2][i] = ((q & 2) ? hi : lo) + got;
                }
            #pragma unroll
            for (int g2 = 0; g2 < 2; ++g2) {
                float lo = k3[g2][0], hi = k3[g2][1];
                float got = __shfl_xor((q & 4) ? lo : hi, 4);
                float z = ((q & 4) ? hi : lo) + got;
                if (g2 == 0) z0 = z; else z1 = z;
            }
        }
        // finalize L1: gp0 lane: z0->i, z1->f ; gp1 lane: z0->g, z1->o
        {
            float2 bi = *(const float2*)&sB1[u][2 * gp];
            float2 wx = *(const float2*)&sWX[u][2 * gp];
            z0 += bi.x + wx.x * x;
            z1 += bi.y + wx.y * x;
            float E = __expf(gp ? 2.0f * z0 : -z0);
            float R = fast_rcp(1.0f + E);
            float v0 = gp ? (1.0f - 2.0f * R) : R;   // gp0: sig(z0)=I, gp1: tanh(z0)=G
            float v1 = sigf(z1);                      // gp0: F, gp1: O
            float e0 = __shfl_xor(v0, 1);             // gp0 gets G, gp1 gets I
            float e1 = __shfl_xor(v1, 1);             // gp0 gets O, gp1 gets F
            float I = gp ? e0 : v0;
            float F = gp ? e1 : v1;
            float G = gp ? v0 : e0;
            float O = gp ? v1 : e1;
            c1 = F * c1 + I * G;                      // identical on both gp lanes
            if (!gp) sH1[nxt][u][my_b] = O * tanhf_(c1);
        }
        __syncthreads();

        // ============ layer 2: W_ih2 @ h1_new + W_hh2 @ h2 ============
        #pragma unroll
        for (int g = 0; g < 4; ++g)
            #pragma unroll
            for (int i = 0; i < 4; ++i) a[g][i] = 0.0f;
        {
            const float* han = &sH1[nxt][0][0] + loff;
            const float* hbc = &sH2[cur][0][0] + loff;
            #pragma unroll
            for (int j = 0; j < 7; ++j) {
                float4 ha = *(const float4*)(han + 64 * j);
                float4 hb = *(const float4*)(hbc + 64 * j);
                #pragma unroll
                for (int g = 0; g < 4; ++g) {
                    a[g][0] += w2a[g][j] * ha.x + w2b[g][j] * hb.x;
                    a[g][1] += w2a[g][j] * ha.y + w2b[g][j] * hb.y;
                    a[g][2] += w2a[g][j] * ha.z + w2b[g][j] * hb.z;
                    a[g][3] += w2a[g][j] * ha.w + w2b[g][j] * hb.w;
                }
            }
        }
        {
            float k2[2][4];
            #pragma unroll
            for (int g2 = 0; g2 < 2; ++g2)
                #pragma unroll
                for (int i = 0; i < 4; ++i) {
                    float lo = a[g2][i], hi = a[g2 + 2][i];
                    float got = __shfl_xor(gp ? lo : hi, 1);
                    k2[g2][i] = (gp ? hi : lo) + got;
                }
            float k3[2][2];
            #pragma unroll
            for (int g2 = 0; g2 < 2; ++g2)
                #pragma unroll
                for (int i = 0; i < 2; ++i) {
                    float lo = k2[g2][i], hi = k2[g2][i + 2];
                    float got = __shfl_xor((q & 2) ? lo : hi, 2);
                    k3[g2][i] = ((q & 2) ? hi : lo) + got;
                }
            #pragma unroll
            for (int g2 = 0; g2 < 2; ++g2) {
                float lo = k3[g2][0], hi = k3[g2][1];
                float got = __shfl_xor((q & 4) ? lo : hi, 4);
                float z = ((q & 4) ? hi : lo) + got;
                if (g2 == 0) z0 = z; else z1 = z;
            }
        }
        {
            float2 bi = *(const float2*)&sB2[u][2 * gp];
            z0 += bi.x;
            z1 += bi.y;
            float E = __expf(gp ? 2.0f * z0 : -z0);
            float R = fast_rcp(1.0f + E);
            float v0 = gp ? (1.0f - 2.0f * R) : R;
            float v1 = sigf(z1);
            float e0 = __shfl_xor(v0, 1);
            float e1 = __shfl_xor(v1, 1);
            float I = gp ? e0 : v0;
            float F = gp ? e1 : v1;
            float G = gp ? v0 : e0;
            float O = gp ? v1 : e1;
            c2 = F * c2 + I * G;
            if (!gp) sH2[nxt][u][my_b] = O * tanhf_(c2);
        }
        __syncthreads();

        // ---- output head: out = W_lin @ h2_new + b_lin (wave 0) ----
        if (tid < 64) {
            const int b = tid >> 3, kc = tid & 7;
            float p = 0.0f;
            #pragma unroll
            for (int jj = 0; jj < 8; ++jj) {
                const int k = kc + 8 * jj;                 // rows >= 51: sWlin = 0
                p += sWlin[k] * sH2[nxt][k][b];
            }
            p += __shfl_xor(p, 1);
            p += __shfl_xor(p, 2);
            p += __shfl_xor(p, 4);
            if (kc == 0) {
                float val = p + blin;
                out[(size_t)(b0 + b) * TTOT + t] = val;
                sXfb[b] = val;
            }
        }
        // sXfb only consumed at t+1 >= TIN; buffer rotation is safe without
        // this barrier otherwise (see R3 analysis).
        if (t >= TIN - 1) __syncthreads();
    }
}

extern "C" void kernel_launch(void* const* d_in, const int* in_sizes, int n_in,
                              void* d_out, int out_size, void* d_ws, size_t ws_size,
                              hipStream_t stream) {
    const float* input = (const float*)d_in[0];
    const float* W_ih1 = (const float*)d_in[1];
    const float* W_hh1 = (const float*)d_in[2];
    const float* b_ih1 = (const float*)d_in[3];
    const float* b_hh1 = (const float*)d_in[4];
    const float* W_ih2 = (const float*)d_in[5];
    const float* W_hh2 = (const float*)d_in[6];
    const float* b_ih2 = (const float*)d_in[7];
    const float* b_hh2 = (const float*)d_in[8];
    const float* W_lin = (const float*)d_in[9];
    const float* b_lin = (const float*)d_in[10];
    // d_in[11] = future (=32), compiled in.
    float* out = (float*)d_out;

    lstm_seq<<<dim3(256), dim3(1024), 0, stream>>>(input, W_ih1, W_hh1, b_ih1, b_hh1,
                                                   W_ih2, W_hh2, b_ih2, b_hh2,
                                                   W_lin, b_lin, out);
}

// Round 6
// 2561.264 us; speedup vs baseline: 1.8722x; 1.8529x over previous
//
#include <hip/hip_runtime.h>

#define H 51
#define TIN 512
#define TTOT 544      // TIN + future(32)
#define BTILE 8

__device__ __forceinline__ float fast_rcp(float x) { return __builtin_amdgcn_rcpf(x); }
__device__ __forceinline__ float sigf(float x)  { return fast_rcp(1.0f + __expf(-x)); }
__device__ __forceinline__ float tanhf_(float x){ return 1.0f - 2.0f * fast_rcp(1.0f + __expf(2.0f * x)); }

// R6: fit the allocator's ACTUAL grant. Observed law: arch VGPRs = 256/waves_per_eu
// (R2/R3: 2 w/EU -> 128; R4/R5: 4 w/EU -> 64). So: 512 thr + waves_per_eu(2,2)
// -> 128 arch (HW-confirmed in R3), and a layout that needs ~125:
//   84 weight floats (4g x 7k x 3 mats, k=q+8j, q in [0,8) -- NO bh duplication),
//   all 8 batches per thread in TWO passes of 4 (16 accumulators at a time),
//   per-lane gate-pair biases in regs (6), c-state 4 regs.
//   lane bits: [0:2]=q, [3:5]=u-low (u = wv*8 + (lane>>3)).
//   R4's HW-verified 3-stage shfl_xor reduce-scatter + gp-pair finalize, per pass.
__global__ __launch_bounds__(512)
__attribute__((amdgpu_waves_per_eu(2, 2)))
void lstm_seq(
    const float* __restrict__ input,   // [2048][512]
    const float* __restrict__ W_ih1,   // [204]
    const float* __restrict__ W_hh1,   // [204][51]
    const float* __restrict__ b_ih1,   // [204]
    const float* __restrict__ b_hh1,   // [204]
    const float* __restrict__ W_ih2,   // [204][51]
    const float* __restrict__ W_hh2,   // [204][51]
    const float* __restrict__ b_ih2,   // [204]
    const float* __restrict__ b_hh2,   // [204]
    const float* __restrict__ W_lin,   // [51]
    const float* __restrict__ b_lin,   // [1]
    float* __restrict__ out)           // [2048][544]
{
    __shared__ __align__(16) float sH1[2][64][8];   // [buf][k/unit][b]
    __shared__ __align__(16) float sH2[2][64][8];
    __shared__ float sWlin[64];
    __shared__ float sXfb[8];

    const int tid  = threadIdx.x;
    const int lane = tid & 63;
    const int wv   = tid >> 6;                 // 0..7
    const int u    = wv * 8 + (lane >> 3);     // 0..63
    const int q    = lane & 7;                 // k-phase
    const int gp   = q & 1;                    // owned gate-pair after butterfly
    const int bA   = ((q & 2) ? 2 : 0) + ((q & 4) ? 1 : 0);  // owned batch, pass 0
    const int b0   = blockIdx.x * BTILE;
    const int ur   = (u < H) ? u : (H - 1);    // clamp pad units (finite garbage)

    // ---- persistent register weights: k = q + 8*j, j in [0,7) ----
    float w1[4][7], w2a[4][7], w2b[4][7];      // 84 floats
    #pragma unroll
    for (int g = 0; g < 4; ++g) {
        const int r = g * H + ur;
        #pragma unroll
        for (int j = 0; j < 7; ++j) {
            const int k = q + 8 * j;
            const bool ok = (k < H);           // zero pad col: kills garbage h[k>=51]
            w1 [g][j] = ok ? W_hh1[r * H + k] : 0.0f;
            w2a[g][j] = ok ? W_ih2[r * H + k] : 0.0f;
            w2b[g][j] = ok ? W_hh2[r * H + k] : 0.0f;
        }
    }
    // per-lane gate-pair constants (this lane only ever finalizes gates 2gp,2gp+1)
    float bi1x, bi1y, wxx, wxy, bi2x, bi2y;
    {
        const int r0 = (2 * gp) * H + ur;
        const int r1 = (2 * gp + 1) * H + ur;
        bi1x = b_ih1[r0] + b_hh1[r0];
        bi1y = b_ih1[r1] + b_hh1[r1];
        wxx  = W_ih1[r0];
        wxy  = W_ih1[r1];
        bi2x = b_ih2[r0] + b_hh2[r0];
        bi2y = b_ih2[r1] + b_hh2[r1];
    }
    const float blin = b_lin[0];

    if (tid < 64) sWlin[tid] = (tid < H) ? W_lin[tid] : 0.0f;
    {
        float* p1 = &sH1[0][0][0];
        float* p2 = &sH2[0][0][0];
        for (int i = tid; i < 2 * 64 * 8; i += 512) { p1[i] = 0.0f; p2[i] = 0.0f; }
    }

    const float* xpA = input + (size_t)(b0 + bA) * TIN;
    const float* xpB = input + (size_t)(b0 + bA + 4) * TIN;
    float c1[2] = {0.0f, 0.0f}, c2[2] = {0.0f, 0.0f};
    __syncthreads();

    for (int t = 0; t < TTOT; ++t) {
        const int cur = t & 1, nxt = cur ^ 1;

        const float xA = (t < TIN) ? xpA[t] : sXfb[bA];
        const float xB = (t < TIN) ? xpB[t] : sXfb[bA + 4];

        // ================= layer 1: W_hh1 @ h1, two 4-batch passes =================
        #pragma unroll
        for (int p = 0; p < 2; ++p) {
            float a[4][4];
            #pragma unroll
            for (int g = 0; g < 4; ++g)
                #pragma unroll
                for (int i = 0; i < 4; ++i) a[g][i] = 0.0f;
            {
                const float* h1c = &sH1[cur][q][4 * p];     // +64 floats per j (imm offs)
                #pragma unroll
                for (int j = 0; j < 7; ++j) {
                    float4 h4 = *(const float4*)(h1c + 64 * j);
                    #pragma unroll
                    for (int g = 0; g < 4; ++g) {
                        a[g][0] += w1[g][j] * h4.x;
                        a[g][1] += w1[g][j] * h4.y;
                        a[g][2] += w1[g][j] * h4.z;
                        a[g][3] += w1[g][j] * h4.w;
                    }
                }
            }
            // 3-stage reduce-scatter over q (HW-verified in R4)
            float z0, z1;
            {
                float k2[2][4];
                #pragma unroll
                for (int g2 = 0; g2 < 2; ++g2)
                    #pragma unroll
                    for (int i = 0; i < 4; ++i) {
                        float lo = a[g2][i], hi = a[g2 + 2][i];
                        float got = __shfl_xor(gp ? lo : hi, 1);
                        k2[g2][i] = (gp ? hi : lo) + got;
                    }
                float k3[2][2];
                #pragma unroll
                for (int g2 = 0; g2 < 2; ++g2)
                    #pragma unroll
                    for (int i = 0; i < 2; ++i) {
                        float lo = k2[g2][i], hi = k2[g2][i + 2];
                        float got = __shfl_xor((q & 2) ? lo : hi, 2);
                        k3[g2][i] = ((q & 2) ? hi : lo) + got;
                    }
                #pragma unroll
                for (int g2 = 0; g2 < 2; ++g2) {
                    float lo = k3[g2][0], hi = k3[g2][1];
                    float got = __shfl_xor((q & 4) ? lo : hi, 4);
                    float z = ((q & 4) ? hi : lo) + got;
                    if (g2 == 0) z0 = z; else z1 = z;
                }
            }
            // finalize pass p: gp0 lane z0->i,z1->f ; gp1 lane z0->g,z1->o
            {
                const float x = p ? xB : xA;
                z0 += bi1x + wxx * x;
                z1 += bi1y + wxy * x;
                float E = __expf(gp ? 2.0f * z0 : -z0);
                float R = fast_rcp(1.0f + E);
                float v0 = gp ? (1.0f - 2.0f * R) : R;   // gp0: I, gp1: G
                float v1 = sigf(z1);                      // gp0: F, gp1: O
                float e0 = __shfl_xor(v0, 1);
                float e1 = __shfl_xor(v1, 1);
                float I = gp ? e0 : v0;
                float F = gp ? e1 : v1;
                float G = gp ? v0 : e0;
                float O = gp ? v1 : e1;
                c1[p] = F * c1[p] + I * G;                // identical on both gp lanes
                if (!gp) sH1[nxt][u][bA + 4 * p] = O * tanhf_(c1[p]);
            }
        }
        __syncthreads();

        // ============ layer 2: W_ih2 @ h1_new + W_hh2 @ h2, two passes ============
        #pragma unroll
        for (int p = 0; p < 2; ++p) {
            float a[4][4];
            #pragma unroll
            for (int g = 0; g < 4; ++g)
                #pragma unroll
                for (int i = 0; i < 4; ++i) a[g][i] = 0.0f;
            {
                const float* han = &sH1[nxt][q][4 * p];
                const float* hbc = &sH2[cur][q][4 * p];
                #pragma unroll
                for (int j = 0; j < 7; ++j) {
                    float4 ha = *(const float4*)(han + 64 * j);
                    float4 hb = *(const float4*)(hbc + 64 * j);
                    #pragma unroll
                    for (int g = 0; g < 4; ++g) {
                        a[g][0] += w2a[g][j] * ha.x + w2b[g][j] * hb.x;
                        a[g][1] += w2a[g][j] * ha.y + w2b[g][j] * hb.y;
                        a[g][2] += w2a[g][j] * ha.z + w2b[g][j] * hb.z;
                        a[g][3] += w2a[g][j] * ha.w + w2b[g][j] * hb.w;
                    }
                }
            }
            float z0, z1;
            {
                float k2[2][4];
                #pragma unroll
                for (int g2 = 0; g2 < 2; ++g2)
                    #pragma unroll
                    for (int i = 0; i < 4; ++i) {
                        float lo = a[g2][i], hi = a[g2 + 2][i];
                        float got = __shfl_xor(gp ? lo : hi, 1);
                        k2[g2][i] = (gp ? hi : lo) + got;
                    }
                float k3[2][2];
                #pragma unroll
                for (int g2 = 0; g2 < 2; ++g2)
                    #pragma unroll
                    for (int i = 0; i < 2; ++i) {
                        float lo = k2[g2][i], hi = k2[g2][i + 2];
                        float got = __shfl_xor((q & 2) ? lo : hi, 2);
                        k3[g2][i] = ((q & 2) ? hi : lo) + got;
                    }
                #pragma unroll
                for (int g2 = 0; g2 < 2; ++g2) {
                    float lo = k3[g2][0], hi = k3[g2][1];
                    float got = __shfl_xor((q & 4) ? lo : hi, 4);
                    float z = ((q & 4) ? hi : lo) + got;
                    if (g2 == 0) z0 = z; else z1 = z;
                }
            }
            {
                z0 += bi2x;
                z1 += bi2y;
                float E = __expf(gp ? 2.0f * z0 : -z0);
                float R = fast_rcp(1.0f + E);
                float v0 = gp ? (1.0f - 2.0f * R) : R;
                float v1 = sigf(z1);
                float e0 = __shfl_xor(v0, 1);
                float e1 = __shfl_xor(v1, 1);
                float I = gp ? e0 : v0;
                float F = gp ? e1 : v1;
                float G = gp ? v0 : e0;
                float O = gp ? v1 : e1;
                c2[p] = F * c2[p] + I * G;
                if (!gp) sH2[nxt][u][bA + 4 * p] = O * tanhf_(c2[p]);
            }
        }
        __syncthreads();

        // ---- output head: out = W_lin @ h2_new + b_lin (wave 0) ----
        if (tid < 64) {
            const int b = tid >> 3, kc = tid & 7;
            float pr = 0.0f;
            #pragma unroll
            for (int jj = 0; jj < 8; ++jj) {
                const int k = kc + 8 * jj;                 // rows >= 51: sWlin = 0
                pr += sWlin[k] * sH2[nxt][k][b];
            }
            pr += __shfl_xor(pr, 1);
            pr += __shfl_xor(pr, 2);
            pr += __shfl_xor(pr, 4);
            if (kc == 0) {
                float val = pr + blin;
                out[(size_t)(b0 + b) * TTOT + t] = val;
                sXfb[b] = val;
            }
        }
        // sXfb only consumed at t+1 >= TIN; buffer rotation safe otherwise (R3 analysis)
        if (t >= TIN - 1) __syncthreads();
    }
}

extern "C" void kernel_launch(void* const* d_in, const int* in_sizes, int n_in,
                              void* d_out, int out_size, void* d_ws, size_t ws_size,
                              hipStream_t stream) {
    const float* input = (const float*)d_in[0];
    const float* W_ih1 = (const float*)d_in[1];
    const float* W_hh1 = (const float*)d_in[2];
    const float* b_ih1 = (const float*)d_in[3];
    const float* b_hh1 = (const float*)d_in[4];
    const float* W_ih2 = (const float*)d_in[5];
    const float* W_hh2 = (const float*)d_in[6];
    const float* b_ih2 = (const float*)d_in[7];
    const float* b_hh2 = (const float*)d_in[8];
    const float* W_lin = (const float*)d_in[9];
    const float* b_lin = (const float*)d_in[10];
    // d_in[11] = future (=32), compiled in.
    float* out = (float*)d_out;

    lstm_seq<<<dim3(256), dim3(512), 0, stream>>>(input, W_ih1, W_hh1, b_ih1, b_hh1,
                                                  W_ih2, W_hh2, b_ih2, b_hh2,
                                                  W_lin, b_lin, out);
}

// Round 7
// 2013.296 us; speedup vs baseline: 2.3817x; 1.2722x over previous
//
#include <hip/hip_runtime.h>

#define H 51
#define TIN 512
#define TTOT 544      // TIN + future(32)
#define BTILE 8
#define ASTRIDE 168   // A-plane row stride in bf16 elems (16B-aligned, bank-friendly)

typedef __attribute__((ext_vector_type(8))) short short8;
typedef __attribute__((ext_vector_type(4))) float float4v;

#define MFMA __builtin_amdgcn_mfma_f32_16x16x32_bf16

__device__ __forceinline__ float fast_rcp(float x) { return __builtin_amdgcn_rcpf(x); }
__device__ __forceinline__ float tanhf_(float x){ return 1.0f - 2.0f * fast_rcp(1.0f + __expf(2.0f * x)); }

// Split f32 into bf16 hi + bf16 lo (RTN both). x ~= hi + lo with residual ~2^-16|x|.
__device__ __forceinline__ void bf16split(float x, unsigned short& hi, unsigned short& lo) {
    unsigned int u  = __float_as_uint(x);
    unsigned int hr = (u + 0x7fffu + ((u >> 16) & 1u)) & 0xffff0000u;
    hi = (unsigned short)(hr >> 16);
    float r = x - __uint_as_float(hr);            // exact
    unsigned int v = __float_as_uint(r);
    lo = (unsigned short)((v + 0x7fffu + ((v >> 16) & 1u)) >> 16);
}

// B-matrix element generators (B[k][n'] = Wcat[n'][k]), n' = u*4+g, u<51 real.
// Layer1 k-space: [0,51)=W_hh1 ; [51,64)=0 (A there holds h2 -> must be 0) ;
//                 k=128: W_ih1 ; k=129: b_ih1+b_hh1 ; else 0.
__device__ float b1val(int k, int u, int g, const float* Whh1, const float* Wih1,
                       const float* bi1, const float* bh1) {
    if (u >= H) return 0.0f;
    int r = g * H + u;
    if (k < H)    return Whh1[r * H + k];
    if (k == 128) return Wih1[r];
    if (k == 129) return bi1[r] + bh1[r];
    return 0.0f;
}
// Layer2 k-space: [0,51)=W_ih2 ; [51,102)=W_hh2 ; k=102: b_ih2+b_hh2 ; else 0.
__device__ float b2val(int k, int u, int g, const float* Wih2, const float* Whh2,
                       const float* bi2, const float* bh2) {
    if (u >= H) return 0.0f;
    int r = g * H + u;
    if (k < H)   return Wih2[r * H + k];
    if (k < 102) return Whh2[r * H + (k - H)];
    if (k == 102) return bi2[r] + bh2[r];
    return 0.0f;
}

// Activation + LSTM cell update for one C tile (16x16).
// lane cols: n_loc = lane&15 = u_loc*4 + g, gate order (i,f,g~,o); rows m = quad*4+i.
// c-state kept consistent on all 4 g-lanes; h valid on g==2 lanes.
__device__ __forceinline__ void act_tile(float4v z, float* cst, float* ho, int lane) {
    const bool isg = ((lane & 3) == 2);
    #pragma unroll
    for (int i = 0; i < 4; ++i) {
        float zz = z[i];
        float E = __expf(isg ? 2.0f * zz : -zz);
        float R = fast_rcp(1.0f + E);
        float v  = isg ? (1.0f - 2.0f * R) : R;   // g0:i g1:f g2:g~ g3:o (sig/tanh)
        float r2 = __shfl_xor(v, 2);              // g0:g~ g1:o g2:i g3:f
        float p  = v * r2;                        // g0,g2: i*g~
        float pp = __shfl_xor(p, 1);              // g1,g3: i*g~
        float fv = (lane & 2) ? r2 : v;           // g1:v=f, g3:r2=f
        float cn = pp + fv * cst[i];              // g1,g3: c_new
        float cb = __shfl_xor(cn, 1);             // g0,g2: c_new
        float cA = (lane & 1) ? cn : cb;          // all: c_new (bit-consistent)
        cst[i] = cA;
        float tc = tanhf_(cA);
        float r1 = __shfl_xor(v, 1);              // g2: o
        ho[i] = tc * r1;                          // valid on g2
    }
}

// 512 thr (8 waves), grid 256, 1 block/CU. Wave w owns n-tiles {w, w+8} of the
// 256-wide gate-interleaved output. Weights: 28 short8 frags/thread (hi/lo bf16),
// built once -> live in AGPR, read natively by MFMA (no accvgpr tax).
__global__ __launch_bounds__(512)
__attribute__((amdgpu_waves_per_eu(2, 2)))
void lstm_seq(
    const float* __restrict__ input,   // [2048][512]
    const float* __restrict__ W_ih1,   // [204]
    const float* __restrict__ W_hh1,   // [204][51]
    const float* __restrict__ b_ih1,   // [204]
    const float* __restrict__ b_hh1,   // [204]
    const float* __restrict__ W_ih2,   // [204][51]
    const float* __restrict__ W_hh2,   // [204][51]
    const float* __restrict__ b_ih2,   // [204]
    const float* __restrict__ b_hh2,   // [204]
    const float* __restrict__ W_lin,   // [51]
    const float* __restrict__ b_lin,   // [1]
    float* __restrict__ out)           // [2048][544]
{
    // A-matrix planes, bf16 hi/lo. cols: 0-50 h1 | 51-101 h2 | 102 one | 103-127 zero
    //                                   | 128 x | 129 one | 130-159 zero | 160-167 pad
    __shared__ __align__(16) unsigned short sAhi[16][ASTRIDE];
    __shared__ __align__(16) unsigned short sAlo[16][ASTRIDE];
    __shared__ float sH2f[64][8];      // h2 f32 for the output head
    __shared__ float sWlin[64];

    const int tid  = threadIdx.x;
    const int lane = tid & 63;
    const int wv   = tid >> 6;             // 0..7
    const int quad = lane >> 4;
    const int kq   = quad * 8;             // k-offset within a 32-wide kt
    const int mrow = lane & 15;            // A-frag row / C col
    const int uloc = (lane >> 2) & 3;
    const int g    = lane & 3;
    const int b0   = blockIdx.x * BTILE;

    // ---- build persistent B fragments (once) ----
    short8 B1h[2][3], B1l[2][3], B2h[2][4], B2l[2][4];
    {
        const int kb1[3] = {0, 32, 128};
        #pragma unroll
        for (int tt = 0; tt < 2; ++tt) {
            const int uu = (wv + 8 * tt) * 4 + uloc;
            #pragma unroll
            for (int kt = 0; kt < 3; ++kt)
                #pragma unroll
                for (int j = 0; j < 8; ++j) {
                    unsigned short hh, hl;
                    bf16split(b1val(kb1[kt] + kq + j, uu, g, W_hh1, W_ih1, b_ih1, b_hh1), hh, hl);
                    B1h[tt][kt][j] = (short)hh; B1l[tt][kt][j] = (short)hl;
                }
            #pragma unroll
            for (int kt = 0; kt < 4; ++kt)
                #pragma unroll
                for (int j = 0; j < 8; ++j) {
                    unsigned short hh, hl;
                    bf16split(b2val(kt * 32 + kq + j, uu, g, W_ih2, W_hh2, b_ih2, b_hh2), hh, hl);
                    B2h[tt][kt][j] = (short)hh; B2l[tt][kt][j] = (short)hl;
                }
        }
    }
    const float blin = b_lin[0];

    // ---- LDS init ----
    {
        unsigned short* pa = &sAhi[0][0];
        unsigned short* pb = &sAlo[0][0];
        for (int i = tid; i < 16 * ASTRIDE; i += 512) { pa[i] = 0; pb[i] = 0; }
        ((float*)sH2f)[tid] = 0.0f;   // 512 == 64*8 exactly
        if (tid < 64) sWlin[tid] = (tid < H) ? W_lin[tid] : 0.0f;
    }
    __syncthreads();
    if (tid < 16) { sAhi[tid][102] = 0x3F80; sAhi[tid][129] = 0x3F80; }  // the "1" cols
    if (tid < 8) {  // x(0)
        unsigned short hh, hl; bf16split(input[(size_t)(b0 + tid) * TIN], hh, hl);
        sAhi[tid][128] = hh; sAlo[tid][128] = hl;
    }

    float c1s[2][4] = {{0,0,0,0},{0,0,0,0}};
    float c2s[2][4] = {{0,0,0,0},{0,0,0,0}};
    __syncthreads();

    for (int t = 0; t < TTOT; ++t) {
        // prefetch next teacher-forced x (head lanes only)
        float xpre = 0.0f;
        if (tid < 64 && (tid & 7) == 0 && t + 1 < TIN)
            xpre = input[(size_t)(b0 + (tid >> 3)) * TIN + t + 1];

        // ---- (1) L1 A-frags: kts {0, 32, 128}, hi+lo ----
        short8 a0h = *(const short8*)&sAhi[mrow][kq];
        short8 a0l = *(const short8*)&sAlo[mrow][kq];
        short8 a1h = *(const short8*)&sAhi[mrow][32 + kq];
        short8 a1l = *(const short8*)&sAlo[mrow][32 + kq];
        short8 axh = *(const short8*)&sAhi[mrow][128 + kq];
        short8 axl = *(const short8*)&sAlo[mrow][128 + kq];
        __syncthreads();                                  // BARRIER A

        // ---- (3) MFMA L1 + activation + h1 writes ----
        {
            float4v C0 = {0,0,0,0}, C1 = {0,0,0,0};
            C0 = MFMA(a0h, B1h[0][0], C0, 0,0,0); C1 = MFMA(a0h, B1h[1][0], C1, 0,0,0);
            C0 = MFMA(a0h, B1l[0][0], C0, 0,0,0); C1 = MFMA(a0h, B1l[1][0], C1, 0,0,0);
            C0 = MFMA(a0l, B1h[0][0], C0, 0,0,0); C1 = MFMA(a0l, B1h[1][0], C1, 0,0,0);
            C0 = MFMA(a1h, B1h[0][1], C0, 0,0,0); C1 = MFMA(a1h, B1h[1][1], C1, 0,0,0);
            C0 = MFMA(a1h, B1l[0][1], C0, 0,0,0); C1 = MFMA(a1h, B1l[1][1], C1, 0,0,0);
            C0 = MFMA(a1l, B1h[0][1], C0, 0,0,0); C1 = MFMA(a1l, B1h[1][1], C1, 0,0,0);
            C0 = MFMA(axh, B1h[0][2], C0, 0,0,0); C1 = MFMA(axh, B1h[1][2], C1, 0,0,0);
            C0 = MFMA(axh, B1l[0][2], C0, 0,0,0); C1 = MFMA(axh, B1l[1][2], C1, 0,0,0);
            C0 = MFMA(axl, B1h[0][2], C0, 0,0,0); C1 = MFMA(axl, B1h[1][2], C1, 0,0,0);
            float h0[4], h1[4];
            act_tile(C0, c1s[0], h0, lane);
            act_tile(C1, c1s[1], h1, lane);
            if (g == 2 && quad < 2) {
                #pragma unroll
                for (int tt = 0; tt < 2; ++tt) {
                    const int uu = (wv + 8 * tt) * 4 + uloc;
                    if (uu < H) {
                        const float* hs = tt ? h1 : h0;
                        #pragma unroll
                        for (int i = 0; i < 4; ++i) {
                            unsigned short hh, hl; bf16split(hs[i], hh, hl);
                            sAhi[quad * 4 + i][uu] = hh; sAlo[quad * 4 + i][uu] = hl;
                        }
                    }
                }
            }
        }
        __syncthreads();                                  // BARRIER B

        // ---- (5) L2 A-frags: kts {0,32,64,96} (h1 new, h2 old, "1") ----
        short8 b0h = *(const short8*)&sAhi[mrow][kq];
        short8 b0l = *(const short8*)&sAlo[mrow][kq];
        short8 b1h_ = *(const short8*)&sAhi[mrow][32 + kq];
        short8 b1l_ = *(const short8*)&sAlo[mrow][32 + kq];
        short8 b2h_ = *(const short8*)&sAhi[mrow][64 + kq];
        short8 b2l_ = *(const short8*)&sAlo[mrow][64 + kq];
        short8 b3h_ = *(const short8*)&sAhi[mrow][96 + kq];
        short8 b3l_ = *(const short8*)&sAlo[mrow][96 + kq];
        __syncthreads();                                  // BARRIER C

        // ---- (7) MFMA L2 + activation + h2 writes ----
        {
            float4v C0 = {0,0,0,0}, C1 = {0,0,0,0};
            C0 = MFMA(b0h, B2h[0][0], C0, 0,0,0); C1 = MFMA(b0h, B2h[1][0], C1, 0,0,0);
            C0 = MFMA(b0h, B2l[0][0], C0, 0,0,0); C1 = MFMA(b0h, B2l[1][0], C1, 0,0,0);
            C0 = MFMA(b0l, B2h[0][0], C0, 0,0,0); C1 = MFMA(b0l, B2h[1][0], C1, 0,0,0);
            C0 = MFMA(b1h_, B2h[0][1], C0, 0,0,0); C1 = MFMA(b1h_, B2h[1][1], C1, 0,0,0);
            C0 = MFMA(b1h_, B2l[0][1], C0, 0,0,0); C1 = MFMA(b1h_, B2l[1][1], C1, 0,0,0);
            C0 = MFMA(b1l_, B2h[0][1], C0, 0,0,0); C1 = MFMA(b1l_, B2h[1][1], C1, 0,0,0);
            C0 = MFMA(b2h_, B2h[0][2], C0, 0,0,0); C1 = MFMA(b2h_, B2h[1][2], C1, 0,0,0);
            C0 = MFMA(b2h_, B2l[0][2], C0, 0,0,0); C1 = MFMA(b2h_, B2l[1][2], C1, 0,0,0);
            C0 = MFMA(b2l_, B2h[0][2], C0, 0,0,0); C1 = MFMA(b2l_, B2h[1][2], C1, 0,0,0);
            C0 = MFMA(b3h_, B2h[0][3], C0, 0,0,0); C1 = MFMA(b3h_, B2h[1][3], C1, 0,0,0);
            C0 = MFMA(b3h_, B2l[0][3], C0, 0,0,0); C1 = MFMA(b3h_, B2l[1][3], C1, 0,0,0);
            C0 = MFMA(b3l_, B2h[0][3], C0, 0,0,0); C1 = MFMA(b3l_, B2h[1][3], C1, 0,0,0);
            float h0[4], h1[4];
            act_tile(C0, c2s[0], h0, lane);
            act_tile(C1, c2s[1], h1, lane);
            if (g == 2 && quad < 2) {
                #pragma unroll
                for (int tt = 0; tt < 2; ++tt) {
                    const int uu = (wv + 8 * tt) * 4 + uloc;
                    if (uu < H) {
                        const float* hs = tt ? h1 : h0;
                        #pragma unroll
                        for (int i = 0; i < 4; ++i) {
                            unsigned short hh, hl; bf16split(hs[i], hh, hl);
                            sAhi[quad * 4 + i][51 + uu] = hh; sAlo[quad * 4 + i][51 + uu] = hl;
                            sH2f[uu][quad * 4 + i] = hs[i];
                        }
                    }
                }
            }
        }
        // teacher-forced x(t+1): value independent of this step -> write pre-barrier
        if (tid < 64 && (tid & 7) == 0 && t + 1 < TIN) {
            unsigned short hh, hl; bf16split(xpre, hh, hl);
            sAhi[tid >> 3][128] = hh; sAlo[tid >> 3][128] = hl;
        }
        __syncthreads();                                  // BARRIER D

        // ---- (9) output head (wave 0) ----
        float val = 0.0f;
        if (tid < 64) {
            const int b = tid >> 3, kc = tid & 7;
            float p = 0.0f;
            #pragma unroll
            for (int jj = 0; jj < 8; ++jj) {
                const int k = kc + 8 * jj;              // k >= 51: sWlin = 0
                p += sWlin[k] * sH2f[k][b];
            }
            p += __shfl_xor(p, 1);
            p += __shfl_xor(p, 2);
            p += __shfl_xor(p, 4);
            if (kc == 0) {
                val = p + blin;
                out[(size_t)(b0 + b) * TTOT + t] = val;
            }
        }
        if (t + 1 >= TIN) {   // autoregressive feedback x(t+1) = out(t)
            if (tid < 64 && (tid & 7) == 0) {
                unsigned short hh, hl; bf16split(val, hh, hl);
                sAhi[tid >> 3][128] = hh; sAlo[tid >> 3][128] = hl;
            }
            __syncthreads();                              // BARRIER E (tail only)
        }
    }
}

extern "C" void kernel_launch(void* const* d_in, const int* in_sizes, int n_in,
                              void* d_out, int out_size, void* d_ws, size_t ws_size,
                              hipStream_t stream) {
    const float* input = (const float*)d_in[0];
    const float* W_ih1 = (const float*)d_in[1];
    const float* W_hh1 = (const float*)d_in[2];
    const float* b_ih1 = (const float*)d_in[3];
    const float* b_hh1 = (const float*)d_in[4];
    const float* W_ih2 = (const float*)d_in[5];
    const float* W_hh2 = (const float*)d_in[6];
    const float* b_ih2 = (const float*)d_in[7];
    const float* b_hh2 = (const float*)d_in[8];
    const float* W_lin = (const float*)d_in[9];
    const float* b_lin = (const float*)d_in[10];
    // d_in[11] = future (=32), compiled in.
    float* out = (float*)d_out;

    lstm_seq<<<dim3(256), dim3(512), 0, stream>>>(input, W_ih1, W_hh1, b_ih1, b_hh1,
                                                  W_ih2, W_hh2, b_ih2, b_hh2,
                                                  W_lin, b_lin, out);
}

// Round 8
// 1088.801 us; speedup vs baseline: 4.4041x; 1.8491x over previous
//
#include <hip/hip_runtime.h>

#define H 51
#define TIN 512
#define TTOT 544      // TIN + future(32)
#define BTILE 8
#define AST 144       // A row stride in shorts (288 B: 16B-aligned, balanced banks)

typedef __attribute__((ext_vector_type(8))) short short8;
typedef __attribute__((ext_vector_type(4))) float float4v;

#define MFMA __builtin_amdgcn_mfma_f32_16x16x32_bf16

__device__ __forceinline__ float fast_rcp(float x) { return __builtin_amdgcn_rcpf(x); }
__device__ __forceinline__ float sigf(float x)  { return fast_rcp(1.0f + __expf(-x)); }
__device__ __forceinline__ float tanhf_(float x){ return 1.0f - 2.0f * fast_rcp(1.0f + __expf(2.0f * x)); }

// Split f32 into bf16 hi + bf16 lo (RTN both). x ~= hi + lo, residual ~2^-16|x|.
__device__ __forceinline__ void bf16split(float x, unsigned short& hi, unsigned short& lo) {
    unsigned int u  = __float_as_uint(x);
    unsigned int hr = (u + 0x7fffu + ((u >> 16) & 1u)) & 0xffff0000u;
    hi = (unsigned short)(hr >> 16);
    float r = x - __uint_as_float(hr);            // exact
    unsigned int v = __float_as_uint(r);
    lo = (unsigned short)((v + 0x7fffu + ((v >> 16) & 1u)) >> 16);
}

// A cols: 0..50 h1 | 51 x | 52..63 zero | 64..114 h2 | 115..127 zero.
// B[k][n], n = unit col. Biases are applied in the act epilogue (NOT in-matmul).
__device__ __forceinline__ float b1val(int k, int u, int g,
                                       const float* Whh1, const float* Wih1) {
    if (u >= H) return 0.0f;
    const int r = g * H + u;
    if (k < H)  return Whh1[r * H + k];
    if (k == H) return Wih1[r];          // x column
    return 0.0f;
}
__device__ __forceinline__ float b2val(int k, int u, int g,
                                       const float* Wih2, const float* Whh2) {
    if (u >= H) return 0.0f;
    const int r = g * H + u;
    if (k < H) return Wih2[r * H + k];
    if (k >= 64 && k < 64 + H) return Whh2[r * H + (k - 64)];
    return 0.0f;
}

// R8: gates are LANE-LOCAL. Wave ut (of 4) owns units ut*16..ut*16+15 and computes
// FOUR C-tiles (one per gate) over those units -> a lane holds z_i,z_f,z_g,z_o of
// its unit in registers. Activation = pure VALU, ZERO shuffles (R7 bottleneck:
// 64 ds_bpermute/wave/step saturated the LDS pipe, SQ_LDS_BANK_CONFLICT 6.5e7).
// 256 thr (4 waves), grid 256, 1 block/CU. 48 B-frags/thread persist in AGPR
// (MFMA reads AGPR natively -> no accvgpr tax). hi/lo bf16 compensation (3 MFMA
// per logical product) keeps absmax at the f32 level (verified R7).
__global__ __launch_bounds__(256)
__attribute__((amdgpu_waves_per_eu(1, 1)))
void lstm_seq(
    const float* __restrict__ input,   // [2048][512]
    const float* __restrict__ W_ih1,   // [204]
    const float* __restrict__ W_hh1,   // [204][51]
    const float* __restrict__ b_ih1,   // [204]
    const float* __restrict__ b_hh1,   // [204]
    const float* __restrict__ W_ih2,   // [204][51]
    const float* __restrict__ W_hh2,   // [204][51]
    const float* __restrict__ b_ih2,   // [204]
    const float* __restrict__ b_hh2,   // [204]
    const float* __restrict__ W_lin,   // [51]
    const float* __restrict__ b_lin,   // [1]
    float* __restrict__ out)           // [2048][544]
{
    __shared__ __align__(16) unsigned short sAhi[16][AST];  // rows = batch (8 used)
    __shared__ __align__(16) unsigned short sAlo[16][AST];
    __shared__ float sH2f[64][8];      // h2 f32 for the output head [unit][batch]
    __shared__ float sWlin[64];

    const int tid  = threadIdx.x;
    const int lane = tid & 63;
    const int ut   = tid >> 6;             // wave id = u-tile 0..3
    const int quad = lane >> 4;
    const int kq   = quad * 8;             // k offset within a 32-wide k-tile
    const int nl   = lane & 15;            // A row (batch) for A-frags; B col for B-frags
    const int u    = ut * 16 + nl;         // this lane's unit (C col)
    const int ur   = (u < H) ? u : (H - 1);
    const int b0   = blockIdx.x * BTILE;

    // ---- persistent B fragments (built once; live in AGPR) ----
    short8 B1h[4][2], B1l[4][2], B2h[4][4], B2l[4][4];
    #pragma unroll
    for (int g = 0; g < 4; ++g) {
        #pragma unroll
        for (int kt = 0; kt < 2; ++kt)
            #pragma unroll
            for (int j = 0; j < 8; ++j) {
                unsigned short hh, hl;
                bf16split(b1val(kt * 32 + kq + j, u, g, W_hh1, W_ih1), hh, hl);
                B1h[g][kt][j] = (short)hh; B1l[g][kt][j] = (short)hl;
            }
        #pragma unroll
        for (int kt = 0; kt < 4; ++kt)
            #pragma unroll
            for (int j = 0; j < 8; ++j) {
                unsigned short hh, hl;
                bf16split(b2val(kt * 32 + kq + j, u, g, W_ih2, W_hh2), hh, hl);
                B2h[g][kt][j] = (short)hh; B2l[g][kt][j] = (short)hl;
            }
    }
    // per-lane epilogue biases (this lane's unit, all 4 gates)
    float zb1[4], zb2[4];
    #pragma unroll
    for (int g = 0; g < 4; ++g) {
        const int r = g * H + ur;
        zb1[g] = b_ih1[r] + b_hh1[r];
        zb2[g] = b_ih2[r] + b_hh2[r];
    }
    const float blin = b_lin[0];

    // ---- LDS init ----
    {
        unsigned short* pa = &sAhi[0][0];
        unsigned short* pb = &sAlo[0][0];
        for (int i = tid; i < 16 * AST; i += 256) { pa[i] = 0; pb[i] = 0; }
        for (int i = tid; i < 64 * 8; i += 256) ((float*)sH2f)[i] = 0.0f;
        if (tid < 64) sWlin[tid] = (tid < H) ? W_lin[tid] : 0.0f;
    }
    __syncthreads();
    if (tid < 8) {  // x(0) at col 51, rows 0..7
        unsigned short hh, hl; bf16split(input[(size_t)(b0 + tid) * TIN], hh, hl);
        sAhi[tid][51] = hh; sAlo[tid][51] = hl;
    }

    float c1[4] = {0,0,0,0}, c2[4] = {0,0,0,0};   // batches quad*4+i (quads 2,3: junk)
    __syncthreads();

    for (int t = 0; t < TTOT; ++t) {
        // prefetch teacher-forced x(t+1)
        float xpre = 0.0f;
        if (tid < 8 && t + 1 < TIN) xpre = input[(size_t)(b0 + tid) * TIN + t + 1];

        // ---- (1) L1 A-frags: cols 0..63 (h1 | x | 0) ----
        short8 a0h = *(const short8*)&sAhi[nl][kq];
        short8 a0l = *(const short8*)&sAlo[nl][kq];
        short8 a1h = *(const short8*)&sAhi[nl][32 + kq];
        short8 a1l = *(const short8*)&sAlo[nl][32 + kq];
        __syncthreads();                                  // BARRIER A

        // teacher-forced x(t+1) -> col 51 (value independent of this step)
        if (tid < 8 && t + 1 < TIN) {
            unsigned short hh, hl; bf16split(xpre, hh, hl);
            sAhi[tid][51] = hh; sAlo[tid][51] = hl;
        }

        // ---- (2) L1 MFMA (6 per gate-tile) + lane-local act + h1 writes ----
        {
            float4v C[4];
            #pragma unroll
            for (int g = 0; g < 4; ++g) {
                float4v c = {0,0,0,0};
                c = MFMA(a0h, B1h[g][0], c, 0,0,0);
                c = MFMA(a0l, B1h[g][0], c, 0,0,0);
                c = MFMA(a0h, B1l[g][0], c, 0,0,0);
                c = MFMA(a1h, B1h[g][1], c, 0,0,0);
                c = MFMA(a1l, B1h[g][1], c, 0,0,0);
                c = MFMA(a1h, B1l[g][1], c, 0,0,0);
                C[g] = c;
            }
            float h1v[4];
            #pragma unroll
            for (int i = 0; i < 4; ++i) {
                float I = sigf  (C[0][i] + zb1[0]);
                float F = sigf  (C[1][i] + zb1[1]);
                float G = tanhf_(C[2][i] + zb1[2]);
                float O = sigf  (C[3][i] + zb1[3]);
                c1[i] = F * c1[i] + I * G;
                h1v[i] = O * tanhf_(c1[i]);
            }
            if (quad < 2 && u < H) {
                #pragma unroll
                for (int i = 0; i < 4; ++i) {
                    unsigned short hh, hl; bf16split(h1v[i], hh, hl);
                    sAhi[quad * 4 + i][u] = hh; sAlo[quad * 4 + i][u] = hl;
                }
            }
        }
        __syncthreads();                                  // BARRIER B

        // ---- (3) L2 A-frags: cols 0..127 (h1new | x | 0 | h2old | 0) ----
        short8 f0h = *(const short8*)&sAhi[nl][kq];
        short8 f0l = *(const short8*)&sAlo[nl][kq];
        short8 f1h = *(const short8*)&sAhi[nl][32 + kq];
        short8 f1l = *(const short8*)&sAlo[nl][32 + kq];
        short8 f2h = *(const short8*)&sAhi[nl][64 + kq];
        short8 f2l = *(const short8*)&sAlo[nl][64 + kq];
        short8 f3h = *(const short8*)&sAhi[nl][96 + kq];
        short8 f3l = *(const short8*)&sAlo[nl][96 + kq];
        __syncthreads();                                  // BARRIER C

        // ---- (4) L2 MFMA (12 per gate-tile) + act + h2 writes ----
        {
            float4v C[4];
            #pragma unroll
            for (int g = 0; g < 4; ++g) {
                float4v c = {0,0,0,0};
                c = MFMA(f0h, B2h[g][0], c, 0,0,0);
                c = MFMA(f0l, B2h[g][0], c, 0,0,0);
                c = MFMA(f0h, B2l[g][0], c, 0,0,0);
                c = MFMA(f1h, B2h[g][1], c, 0,0,0);
                c = MFMA(f1l, B2h[g][1], c, 0,0,0);
                c = MFMA(f1h, B2l[g][1], c, 0,0,0);
                c = MFMA(f2h, B2h[g][2], c, 0,0,0);
                c = MFMA(f2l, B2h[g][2], c, 0,0,0);
                c = MFMA(f2h, B2l[g][2], c, 0,0,0);
                c = MFMA(f3h, B2h[g][3], c, 0,0,0);
                c = MFMA(f3l, B2h[g][3], c, 0,0,0);
                c = MFMA(f3h, B2l[g][3], c, 0,0,0);
                C[g] = c;
            }
            float h2v[4];
            #pragma unroll
            for (int i = 0; i < 4; ++i) {
                float I = sigf  (C[0][i] + zb2[0]);
                float F = sigf  (C[1][i] + zb2[1]);
                float G = tanhf_(C[2][i] + zb2[2]);
                float O = sigf  (C[3][i] + zb2[3]);
                c2[i] = F * c2[i] + I * G;
                h2v[i] = O * tanhf_(c2[i]);
            }
            if (quad < 2 && u < H) {
                #pragma unroll
                for (int i = 0; i < 4; ++i) {
                    unsigned short hh, hl; bf16split(h2v[i], hh, hl);
                    sAhi[quad * 4 + i][64 + u] = hh; sAlo[quad * 4 + i][64 + u] = hl;
                    sH2f[u][quad * 4 + i] = h2v[i];
                }
            }
        }
        __syncthreads();                                  // BARRIER D

        // ---- (5) output head (wave 0 only; sH2f disjoint from sA reads) ----
        float val = 0.0f;
        if (tid < 64) {
            const int b = tid >> 3, kc = tid & 7;
            float p = 0.0f;
            #pragma unroll
            for (int jj = 0; jj < 8; ++jj) {
                const int k = kc + 8 * jj;              // k >= 51: sWlin = 0
                p += sWlin[k] * sH2f[k][b];
            }
            p += __shfl_xor(p, 1);
            p += __shfl_xor(p, 2);
            p += __shfl_xor(p, 4);
            if (kc == 0) {
                val = p + blin;
                out[(size_t)(b0 + b) * TTOT + t] = val;
            }
        }
        if (t >= TIN - 1) {   // autoregressive feedback x(t+1) = out(t)
            if (tid < 64 && (tid & 7) == 0) {
                unsigned short hh, hl; bf16split(val, hh, hl);
                sAhi[tid >> 3][51] = hh; sAlo[tid >> 3][51] = hl;
            }
            __syncthreads();                              // BARRIER E (tail only)
        }
    }
}

extern "C" void kernel_launch(void* const* d_in, const int* in_sizes, int n_in,
                              void* d_out, int out_size, void* d_ws, size_t ws_size,
                              hipStream_t stream) {
    const float* input = (const float*)d_in[0];
    const float* W_ih1 = (const float*)d_in[1];
    const float* W_hh1 = (const float*)d_in[2];
    const float* b_ih1 = (const float*)d_in[3];
    const float* b_hh1 = (const float*)d_in[4];
    const float* W_ih2 = (const float*)d_in[5];
    const float* W_hh2 = (const float*)d_in[6];
    const float* b_ih2 = (const float*)d_in[7];
    const float* b_hh2 = (const float*)d_in[8];
    const float* W_lin = (const float*)d_in[9];
    const float* b_lin = (const float*)d_in[10];
    // d_in[11] = future (=32), compiled in.
    float* out = (float*)d_out;

    lstm_seq<<<dim3(256), dim3(256), 0, stream>>>(input, W_ih1, W_hh1, b_ih1, b_hh1,
                                                  W_ih2, W_hh2, b_ih2, b_hh2,
                                                  W_lin, b_lin, out);
}